// Round 1
// baseline (828.764 us; speedup 1.0000x reference)
//
#include <hip/hip_runtime.h>
#include <math.h>

#define NSEQ   2048
#define DMODEL 1024
#define NHEADS 16
#define HD     64

// ---------------------------------------------------------------------------
// GEMM (B-transposed layout): C[m,n] = sum_k A[m,k] * B[n,k]
// A:[M][K] row-major, B:[N][K] row-major, C:[M][N] row-major.
// Tile BM=BN=64, BK=32; 256 threads; 4x4 register tile per thread.
// ---------------------------------------------------------------------------
__global__ __launch_bounds__(256) void gemm_bt_f32(
    const float* __restrict__ A, const float* __restrict__ B,
    float* __restrict__ C, int M, int N, int K)
{
    __shared__ float As[32][68];   // [k][m], padded (68*4B = 272B, 16B-aligned rows)
    __shared__ float Bs[32][68];   // [k][n]

    const int bm = blockIdx.x * 64;
    const int bn = blockIdx.y * 64;
    const int t  = threadIdx.x;
    const int tx = t & 15;
    const int ty = t >> 4;

    float acc[4][4];
#pragma unroll
    for (int i = 0; i < 4; ++i)
#pragma unroll
        for (int j = 0; j < 4; ++j) acc[i][j] = 0.f;

    for (int k0 = 0; k0 < K; k0 += 32) {
        // Stage A,B tiles (64 rows x 32 k each). 512 float4 loads per operand,
        // 2 per thread, coalesced over k-fastest.
#pragma unroll
        for (int c = 0; c < 2; ++c) {
            const int fi  = c * 256 + t;   // 0..511
            const int row = fi >> 3;       // 0..63
            const int kq  = fi & 7;        // 0..7  (k = kq*4 .. kq*4+3)
            const float4 av = *reinterpret_cast<const float4*>(
                &A[(size_t)(bm + row) * K + k0 + kq * 4]);
            As[kq * 4 + 0][row] = av.x;
            As[kq * 4 + 1][row] = av.y;
            As[kq * 4 + 2][row] = av.z;
            As[kq * 4 + 3][row] = av.w;
            const float4 bv = *reinterpret_cast<const float4*>(
                &B[(size_t)(bn + row) * K + k0 + kq * 4]);
            Bs[kq * 4 + 0][row] = bv.x;
            Bs[kq * 4 + 1][row] = bv.y;
            Bs[kq * 4 + 2][row] = bv.z;
            Bs[kq * 4 + 3][row] = bv.w;
        }
        __syncthreads();

#pragma unroll
        for (int k = 0; k < 32; ++k) {
            const float4 a4 = *reinterpret_cast<const float4*>(&As[k][ty * 4]);
            const float4 b4 = *reinterpret_cast<const float4*>(&Bs[k][tx * 4]);
            const float a[4] = {a4.x, a4.y, a4.z, a4.w};
            const float b[4] = {b4.x, b4.y, b4.z, b4.w};
#pragma unroll
            for (int i = 0; i < 4; ++i)
#pragma unroll
                for (int j = 0; j < 4; ++j)
                    acc[i][j] = fmaf(a[i], b[j], acc[i][j]);
        }
        __syncthreads();
    }

#pragma unroll
    for (int i = 0; i < 4; ++i) {
        const float4 o = make_float4(acc[i][0], acc[i][1], acc[i][2], acc[i][3]);
        *reinterpret_cast<float4*>(
            &C[(size_t)(bm + ty * 4 + i) * N + bn + tx * 4]) = o;
    }
}

// ---------------------------------------------------------------------------
// Per-head squared norms: qn[h*NSEQ+n] = sum_d Q[n][h*64+d]^2 (same for K).
// ---------------------------------------------------------------------------
__global__ void norms_kernel(const float* __restrict__ Q,
                             const float* __restrict__ K,
                             float* __restrict__ qn, float* __restrict__ kn)
{
    const int idx   = blockIdx.x * blockDim.x + threadIdx.x;
    const int total = NHEADS * NSEQ;
    if (idx >= 2 * total) return;
    const bool isK = idx >= total;
    const int  r   = isK ? idx - total : idx;
    const int  h   = r >> 11;            // r / NSEQ
    const int  n   = r & (NSEQ - 1);
    const float* src = (isK ? K : Q) + (size_t)n * DMODEL + h * HD;
    float s = 0.f;
#pragma unroll
    for (int d = 0; d < HD; d += 4) {
        const float4 v = *reinterpret_cast<const float4*>(&src[d]);
        s = fmaf(v.x, v.x, s); s = fmaf(v.y, v.y, s);
        s = fmaf(v.z, v.z, s); s = fmaf(v.w, v.w, s);
    }
    (isK ? kn : qn)[r] = s;
}

// ---------------------------------------------------------------------------
// Fused hyperbolic attention, flash-style.
// Grid: (NSEQ/64 q-tiles, NHEADS). Block: 256 threads (tx 0..15, ty 0..15).
// Each thread owns a 4x4 tile of S/P and a 4(rows) x 4(dims) tile of O.
// KVs buffer is time-shared: K-transposed during S phase, V during PV phase.
// ---------------------------------------------------------------------------
__global__ __launch_bounds__(256) void hyp_attn_kernel(
    const float* __restrict__ Q, const float* __restrict__ K,
    const float* __restrict__ V, const float* __restrict__ qn,
    const float* __restrict__ kn, float* __restrict__ O)
{
    __shared__ float Qs[64][64];   // [d][i]
    __shared__ float KVs[64][64];  // S phase: [d][j] (K^T); PV phase: [j][d] (V)
    __shared__ float Ps[64][68];   // [i][j], padded

    const int h  = blockIdx.y;
    const int n0 = blockIdx.x * 64;
    const int t  = threadIdx.x;
    const int tx = t & 15;
    const int ty = t >> 4;

    // Load Q tile transposed into LDS.
    {
        const int i  = t >> 2;
        const int d0 = (t & 3) * 16;
        const float* src = &Q[(size_t)(n0 + i) * DMODEL + h * HD + d0];
#pragma unroll
        for (int c = 0; c < 16; ++c) Qs[d0 + c][i] = src[c];
    }

    float qn_r[4], m_i[4], l_i[4], o_acc[4][4];
#pragma unroll
    for (int ii = 0; ii < 4; ++ii) {
        qn_r[ii] = qn[h * NSEQ + n0 + ty * 4 + ii];
        m_i[ii]  = -INFINITY;
        l_i[ii]  = 0.f;
#pragma unroll
        for (int jj = 0; jj < 4; ++jj) o_acc[ii][jj] = 0.f;
    }
    __syncthreads();

    for (int jt = 0; jt < NSEQ / 64; ++jt) {
        // ---- stage K tile (transposed) ----
        {
            const int j  = t >> 2;
            const int d0 = (t & 3) * 16;
            const float* src = &K[(size_t)(jt * 64 + j) * DMODEL + h * HD + d0];
#pragma unroll
            for (int c = 0; c < 16; ++c) KVs[d0 + c][j] = src[c];
        }
        __syncthreads();

        // ---- S = Q K^T (4x4 per thread) ----
        float s[4][4];
#pragma unroll
        for (int ii = 0; ii < 4; ++ii)
#pragma unroll
            for (int jj = 0; jj < 4; ++jj) s[ii][jj] = 0.f;
#pragma unroll 8
        for (int d = 0; d < 64; ++d) {
            const float4 a4 = *reinterpret_cast<const float4*>(&Qs[d][ty * 4]);
            const float4 b4 = *reinterpret_cast<const float4*>(&KVs[d][tx * 4]);
            const float a[4] = {a4.x, a4.y, a4.z, a4.w};
            const float b[4] = {b4.x, b4.y, b4.z, b4.w};
#pragma unroll
            for (int ii = 0; ii < 4; ++ii)
#pragma unroll
                for (int jj = 0; jj < 4; ++jj)
                    s[ii][jj] = fmaf(a[ii], b[jj], s[ii][jj]);
        }

        // ---- hyperbolic distance ----
        float kn_c[4];
#pragma unroll
        for (int jj = 0; jj < 4; ++jj)
            kn_c[jj] = kn[h * NSEQ + jt * 64 + tx * 4 + jj];

        float tm[4];
#pragma unroll
        for (int ii = 0; ii < 4; ++ii) {
            float tmax = -INFINITY;
#pragma unroll
            for (int jj = 0; jj < 4; ++jj) {
                const float qk  = s[ii][jj];
                const float dsq = fmaxf(qn_r[ii] + kn_c[jj] - 2.f * qk, 0.f);
                const float den = fmaxf((1.f - qn_r[ii]) * (1.f - kn_c[jj]), 1e-6f);
                const float ca  = fmaxf(1.f + 2.f * dsq / den, 1.f);
                const float dist = (ca > 1.f) ? acoshf(fmaxf(ca, 1.f + 1e-12f)) : 0.f;
                s[ii][jj] = -dist;
                tmax = fmaxf(tmax, -dist);
            }
            tm[ii] = tmax;
        }

        // ---- online softmax (reduce across the 16-lane tx group) ----
#pragma unroll
        for (int off = 8; off > 0; off >>= 1)
#pragma unroll
            for (int ii = 0; ii < 4; ++ii)
                tm[ii] = fmaxf(tm[ii], __shfl_xor(tm[ii], off));

        float alpha[4], p[4][4], rs[4];
#pragma unroll
        for (int ii = 0; ii < 4; ++ii) {
            const float nm = fmaxf(m_i[ii], tm[ii]);
            alpha[ii] = expf(m_i[ii] - nm);   // exp(-inf) = 0 on first tile
            m_i[ii]   = nm;
            float r = 0.f;
#pragma unroll
            for (int jj = 0; jj < 4; ++jj) {
                p[ii][jj] = expf(s[ii][jj] - nm);
                r += p[ii][jj];
            }
            rs[ii] = r;
        }
#pragma unroll
        for (int off = 8; off > 0; off >>= 1)
#pragma unroll
            for (int ii = 0; ii < 4; ++ii)
                rs[ii] += __shfl_xor(rs[ii], off);
#pragma unroll
        for (int ii = 0; ii < 4; ++ii) {
            l_i[ii] = l_i[ii] * alpha[ii] + rs[ii];
#pragma unroll
            for (int jj = 0; jj < 4; ++jj) o_acc[ii][jj] *= alpha[ii];
            *reinterpret_cast<float4*>(&Ps[ty * 4 + ii][tx * 4]) =
                make_float4(p[ii][0], p[ii][1], p[ii][2], p[ii][3]);
        }
        __syncthreads();   // Ps written; KVs (K^T) no longer needed

        // ---- stage V tile (natural layout) into KVs ----
        {
            const int j  = t >> 2;
            const int d0 = (t & 3) * 16;
            const float* src = &V[(size_t)(jt * 64 + j) * DMODEL + h * HD + d0];
#pragma unroll
            for (int c = 0; c < 4; ++c)
                *reinterpret_cast<float4*>(&KVs[j][d0 + c * 4]) =
                    *reinterpret_cast<const float4*>(&src[c * 4]);
        }
        __syncthreads();

        // ---- O += P V ----
#pragma unroll 8
        for (int j = 0; j < 64; ++j) {
            const float4 v4 = *reinterpret_cast<const float4*>(&KVs[j][tx * 4]);
#pragma unroll
            for (int ii = 0; ii < 4; ++ii) {
                const float pv = Ps[ty * 4 + ii][j];
                o_acc[ii][0] = fmaf(pv, v4.x, o_acc[ii][0]);
                o_acc[ii][1] = fmaf(pv, v4.y, o_acc[ii][1]);
                o_acc[ii][2] = fmaf(pv, v4.z, o_acc[ii][2]);
                o_acc[ii][3] = fmaf(pv, v4.w, o_acc[ii][3]);
            }
        }
        __syncthreads();   // before next tile overwrites KVs/Ps
    }

    // ---- epilogue: normalize and write O (merged-head layout [n][dm]) ----
#pragma unroll
    for (int ii = 0; ii < 4; ++ii) {
        const float inv = 1.f / l_i[ii];
        const float4 o = make_float4(o_acc[ii][0] * inv, o_acc[ii][1] * inv,
                                     o_acc[ii][2] * inv, o_acc[ii][3] * inv);
        *reinterpret_cast<float4*>(
            &O[(size_t)(n0 + ty * 4 + ii) * DMODEL + h * HD + tx * 4]) = o;
    }
}

// ---------------------------------------------------------------------------
extern "C" void kernel_launch(void* const* d_in, const int* in_sizes, int n_in,
                              void* d_out, int out_size, void* d_ws, size_t ws_size,
                              hipStream_t stream)
{
    const float* x  = (const float*)d_in[0];
    const float* Wq = (const float*)d_in[1];
    const float* Wk = (const float*)d_in[2];
    const float* Wv = (const float*)d_in[3];
    const float* Wo = (const float*)d_in[4];
    float* out = (float*)d_out;

    float* ws = (float*)d_ws;
    const size_t MAT = (size_t)NSEQ * DMODEL;   // 2M floats
    float* Q  = ws;
    float* K  = ws + MAT;
    float* V  = ws + 2 * MAT;
    float* O  = ws + 3 * MAT;
    float* qn = ws + 4 * MAT;                   // NHEADS*NSEQ floats
    float* kn = qn + NHEADS * NSEQ;             // NHEADS*NSEQ floats

    const dim3 blk(256);
    const dim3 gg(NSEQ / 64, DMODEL / 64);

    gemm_bt_f32<<<gg, blk, 0, stream>>>(x, Wq, Q, NSEQ, DMODEL, DMODEL);
    gemm_bt_f32<<<gg, blk, 0, stream>>>(x, Wk, K, NSEQ, DMODEL, DMODEL);
    gemm_bt_f32<<<gg, blk, 0, stream>>>(x, Wv, V, NSEQ, DMODEL, DMODEL);

    norms_kernel<<<(2 * NHEADS * NSEQ + 255) / 256, 256, 0, stream>>>(Q, K, qn, kn);

    hyp_attn_kernel<<<dim3(NSEQ / 64, NHEADS), blk, 0, stream>>>(Q, K, V, qn, kn, O);

    gemm_bt_f32<<<gg, blk, 0, stream>>>(O, Wo, out, NSEQ, DMODEL, DMODEL);
}

// Round 4
// 370.340 us; speedup vs baseline: 2.2378x; 2.2378x over previous
//
#include <hip/hip_runtime.h>
#include <math.h>

#define NSEQ   2048
#define DMODEL 1024
#define NHEADS 16
#define HD     64

typedef short bf16x8 __attribute__((ext_vector_type(8)));
typedef float f32x4  __attribute__((ext_vector_type(4)));
typedef unsigned short ushort8_t __attribute__((ext_vector_type(8)));

// RTNE float -> bf16 bits
__device__ __forceinline__ unsigned short f2bf(float x) {
    unsigned int u = __builtin_bit_cast(unsigned int, x);
    unsigned int r = (u + 0x7FFFu + ((u >> 16) & 1u)) >> 16;
    return (unsigned short)r;
}

// ---------------------------------------------------------------------------
// fp32 GEMM (B-transposed): C[m,n] = sum_k A[m,k]*B[n,k]. 64x64 tile, BK=32.
// ---------------------------------------------------------------------------
__global__ __launch_bounds__(256) void gemm_bt_f32(
    const float* __restrict__ A, const float* __restrict__ B,
    float* __restrict__ C, int M, int N, int K)
{
    __shared__ float As[32][68];
    __shared__ float Bs[32][68];

    const int bm = blockIdx.x * 64;
    const int bn = blockIdx.y * 64;
    const int t  = threadIdx.x;
    const int tx = t & 15;
    const int ty = t >> 4;

    float acc[4][4];
#pragma unroll
    for (int i = 0; i < 4; ++i)
#pragma unroll
        for (int j = 0; j < 4; ++j) acc[i][j] = 0.f;

    for (int k0 = 0; k0 < K; k0 += 32) {
#pragma unroll
        for (int c = 0; c < 2; ++c) {
            const int fi  = c * 256 + t;
            const int row = fi >> 3;
            const int kq  = fi & 7;
            const float4 av = *reinterpret_cast<const float4*>(
                &A[(size_t)(bm + row) * K + k0 + kq * 4]);
            As[kq * 4 + 0][row] = av.x;
            As[kq * 4 + 1][row] = av.y;
            As[kq * 4 + 2][row] = av.z;
            As[kq * 4 + 3][row] = av.w;
            const float4 bv = *reinterpret_cast<const float4*>(
                &B[(size_t)(bn + row) * K + k0 + kq * 4]);
            Bs[kq * 4 + 0][row] = bv.x;
            Bs[kq * 4 + 1][row] = bv.y;
            Bs[kq * 4 + 2][row] = bv.z;
            Bs[kq * 4 + 3][row] = bv.w;
        }
        __syncthreads();

#pragma unroll
        for (int k = 0; k < 32; ++k) {
            const float4 a4 = *reinterpret_cast<const float4*>(&As[k][ty * 4]);
            const float4 b4 = *reinterpret_cast<const float4*>(&Bs[k][tx * 4]);
            const float a[4] = {a4.x, a4.y, a4.z, a4.w};
            const float b[4] = {b4.x, b4.y, b4.z, b4.w};
#pragma unroll
            for (int i = 0; i < 4; ++i)
#pragma unroll
                for (int j = 0; j < 4; ++j)
                    acc[i][j] = fmaf(a[i], b[j], acc[i][j]);
        }
        __syncthreads();
    }

#pragma unroll
    for (int i = 0; i < 4; ++i) {
        const float4 o = make_float4(acc[i][0], acc[i][1], acc[i][2], acc[i][3]);
        *reinterpret_cast<float4*>(
            &C[(size_t)(bm + ty * 4 + i) * N + bn + tx * 4]) = o;
    }
}

// ---------------------------------------------------------------------------
// Per-head norms + reciprocals: qn, cq=1/(1-qn); kn, ck=1/(1-kn).
// ---------------------------------------------------------------------------
__global__ void norms_kernel(const float* __restrict__ Q,
                             const float* __restrict__ K,
                             float* __restrict__ qn, float* __restrict__ cq,
                             float* __restrict__ kn, float* __restrict__ ck)
{
    const int idx   = blockIdx.x * blockDim.x + threadIdx.x;
    const int total = NHEADS * NSEQ;
    if (idx >= 2 * total) return;
    const bool isK = idx >= total;
    const int  r   = isK ? idx - total : idx;
    const int  h   = r >> 11;
    const int  n   = r & (NSEQ - 1);
    const float* src = (isK ? K : Q) + (size_t)n * DMODEL + h * HD;
    float s = 0.f;
#pragma unroll
    for (int d = 0; d < HD; d += 4) {
        const float4 v = *reinterpret_cast<const float4*>(&src[d]);
        s = fmaf(v.x, v.x, s); s = fmaf(v.y, v.y, s);
        s = fmaf(v.z, v.z, s); s = fmaf(v.w, v.w, s);
    }
    (isK ? kn : qn)[r] = s;
    (isK ? ck : cq)[r] = 1.0f / (1.0f - s);
}

// ---------------------------------------------------------------------------
// Split fp32 Q,K into bf16 hi/lo pairs (hi = bf16(x), lo = bf16(x - hi)).
// ---------------------------------------------------------------------------
__global__ void split_qk(const float* __restrict__ Qf, const float* __restrict__ Kf,
                         unsigned short* __restrict__ Qh, unsigned short* __restrict__ Ql,
                         unsigned short* __restrict__ Kh, unsigned short* __restrict__ Kl)
{
    const size_t i4 = ((size_t)blockIdx.x * blockDim.x + threadIdx.x) * 4;
    if (i4 >= (size_t)NSEQ * DMODEL) return;
    const float4 qv = *reinterpret_cast<const float4*>(Qf + i4);
    const float4 kv = *reinterpret_cast<const float4*>(Kf + i4);
    const float qa[4] = {qv.x, qv.y, qv.z, qv.w};
    const float ka[4] = {kv.x, kv.y, kv.z, kv.w};
    ushort4 qh, ql, kh, kl;
    unsigned short* qhp = &qh.x; unsigned short* qlp = &ql.x;
    unsigned short* khp = &kh.x; unsigned short* klp = &kl.x;
#pragma unroll
    for (int c = 0; c < 4; ++c) {
        const unsigned short h1 = f2bf(qa[c]);
        const float hf1 = __builtin_bit_cast(float, (unsigned int)h1 << 16);
        qhp[c] = h1; qlp[c] = f2bf(qa[c] - hf1);
        const unsigned short h2 = f2bf(ka[c]);
        const float hf2 = __builtin_bit_cast(float, (unsigned int)h2 << 16);
        khp[c] = h2; klp[c] = f2bf(ka[c] - hf2);
    }
    *reinterpret_cast<ushort4*>(Qh + i4) = qh;
    *reinterpret_cast<ushort4*>(Ql + i4) = ql;
    *reinterpret_cast<ushort4*>(Kh + i4) = kh;
    *reinterpret_cast<ushort4*>(Kl + i4) = kl;
}

// ---------------------------------------------------------------------------
// MFMA hyperbolic attention — LOCALIZATION BUILD (minimum assumptions).
// Plain reg-staged LDS (padded rows, no swizzle, no global_load_lds).
// V transposed to bf16 in-kernel (no separate Vt pass/buffer).
// P goes through wave-private LDS with explicit [j][q] indexing (no shuffles).
// Math identical to R3: S^T=mfma(K,Q) 3-pass split-bf16;
// w = 1/(ca+sqrt(ca^2-1)) = exp(-acosh(ca)); PV: O^T = mfma(V^T, P).
// ---------------------------------------------------------------------------
__global__ __launch_bounds__(256) void hyp_attn_simple(
    const unsigned short* __restrict__ Qh, const unsigned short* __restrict__ Ql,
    const unsigned short* __restrict__ Kh, const unsigned short* __restrict__ Kl,
    const float* __restrict__ Vf,
    const float* __restrict__ qn_a, const float* __restrict__ cq_a,
    const float* __restrict__ kn_a, const float* __restrict__ ck_a,
    float* __restrict__ O)
{
    __shared__ unsigned short Khs[64 * 72];   // [j][d], pad 8
    __shared__ unsigned short Kls[64 * 72];
    __shared__ unsigned short Vts[64 * 72];   // [d][j] (V^T), pad 8
    __shared__ unsigned short PsB[4 * 64 * 24]; // per-wave [j][q], pad 8
    __shared__ float kns[64];
    __shared__ float cks[64];

    const int h    = blockIdx.y;
    const int n0   = blockIdx.x * 64;
    const int t    = threadIdx.x;
    const int wid  = t >> 6;
    const int lane = t & 63;
    const int g    = lane >> 4;
    const int r    = lane & 15;
    const int q    = n0 + wid * 16 + r;

    // Q fragments (hi/lo), 2 d-chunks of K=32
    bf16x8 qfh[2], qfl[2];
#pragma unroll
    for (int dc = 0; dc < 2; ++dc) {
        const size_t off = (size_t)q * DMODEL + h * HD + dc * 32 + g * 8;
        qfh[dc] = *reinterpret_cast<const bf16x8*>(Qh + off);
        qfl[dc] = *reinterpret_cast<const bf16x8*>(Ql + off);
    }
    const float qn_l = qn_a[h * NSEQ + q];
    const float cq2  = 2.0f * cq_a[h * NSEQ + q];

    unsigned short* Pw = PsB + wid * (64 * 24);

    f32x4 oacc[4];
#pragma unroll
    for (int dt = 0; dt < 4; ++dt) oacc[dt] = (f32x4){0.f, 0.f, 0.f, 0.f};
    float l_acc = 0.f;

    for (int jb = 0; jb < NSEQ / 64; ++jb) {
        const int j0 = jb * 64;
        __syncthreads();   // previous tile fully consumed by all waves

        // ---- stage K hi/lo ([j][d]) and V^T ([d][j], f32->bf16) ----
        {
            const int j  = t >> 2;
            const int dq = (t & 3) * 16;
            const ushort8_t* skh = reinterpret_cast<const ushort8_t*>(
                Kh + (size_t)(j0 + j) * DMODEL + h * HD + dq);
            const ushort8_t* skl = reinterpret_cast<const ushort8_t*>(
                Kl + (size_t)(j0 + j) * DMODEL + h * HD + dq);
            *reinterpret_cast<ushort8_t*>(&Khs[j * 72 + dq])     = skh[0];
            *reinterpret_cast<ushort8_t*>(&Khs[j * 72 + dq + 8]) = skh[1];
            *reinterpret_cast<ushort8_t*>(&Kls[j * 72 + dq])     = skl[0];
            *reinterpret_cast<ushort8_t*>(&Kls[j * 72 + dq + 8]) = skl[1];
            const float4* vsrc = reinterpret_cast<const float4*>(
                Vf + (size_t)(j0 + j) * DMODEL + h * HD + dq);
#pragma unroll
            for (int c4 = 0; c4 < 4; ++c4) {
                const float4 v = vsrc[c4];
                Vts[(dq + c4 * 4 + 0) * 72 + j] = f2bf(v.x);
                Vts[(dq + c4 * 4 + 1) * 72 + j] = f2bf(v.y);
                Vts[(dq + c4 * 4 + 2) * 72 + j] = f2bf(v.z);
                Vts[(dq + c4 * 4 + 3) * 72 + j] = f2bf(v.w);
            }
            if (t < 64)       kns[t]      = kn_a[h * NSEQ + j0 + t];
            else if (t < 128) cks[t - 64] = ck_a[h * NSEQ + j0 + t - 64];
        }
        __syncthreads();

        // ---- S^T tiles + distance -> P (bf16, wave-private LDS) ----
#pragma unroll
        for (int jt = 0; jt < 4; ++jt) {
            f32x4 sac = (f32x4){0.f, 0.f, 0.f, 0.f};
#pragma unroll
            for (int dc = 0; dc < 2; ++dc) {
                const int row = jt * 16 + r;
                const bf16x8 kh = *reinterpret_cast<const bf16x8*>(
                    &Khs[row * 72 + dc * 32 + g * 8]);
                const bf16x8 kl = *reinterpret_cast<const bf16x8*>(
                    &Kls[row * 72 + dc * 32 + g * 8]);
                sac = __builtin_amdgcn_mfma_f32_16x16x32_bf16(kh, qfh[dc], sac, 0, 0, 0);
                sac = __builtin_amdgcn_mfma_f32_16x16x32_bf16(kh, qfl[dc], sac, 0, 0, 0);
                sac = __builtin_amdgcn_mfma_f32_16x16x32_bf16(kl, qfh[dc], sac, 0, 0, 0);
            }
#pragma unroll
            for (int rg = 0; rg < 4; ++rg) {
                const int jl = jt * 16 + g * 4 + rg;   // D-map: row=(l>>4)*4+reg
                const float kn_v = kns[jl];
                const float ck_v = cks[jl];
                const float qk  = sac[rg];
                const float dsq = fmaxf(fmaf(-2.f, qk, qn_l + kn_v), 0.f);
                const float ca  = fmaxf(fmaf(dsq, cq2 * ck_v, 1.f), 1.0f);
                const float s2  = fmaxf(fmaf(ca, ca, -1.f), 0.f);
                const float wj  = __builtin_amdgcn_rcpf(ca + __builtin_amdgcn_sqrtf(s2));
                l_acc += wj;
                Pw[jl * 24 + r] = f2bf(wj);            // P[j][q], q = r (D-map col)
            }
        }
        // Pw is wave-private: within-wave ds_write->ds_read ordering suffices.

        // ---- PV: O^T += V^T * P ----
#pragma unroll
        for (int kc = 0; kc < 2; ++kc) {
            union { unsigned short s[8]; bf16x8 v; } pb;
#pragma unroll
            for (int e = 0; e < 8; ++e)
                pb.s[e] = Pw[(kc * 32 + g * 8 + e) * 24 + r];  // B: k=8g+e, n=r
#pragma unroll
            for (int dt = 0; dt < 4; ++dt) {
                const bf16x8 va = *reinterpret_cast<const bf16x8*>(
                    &Vts[(dt * 16 + r) * 72 + kc * 32 + g * 8]); // A: m=r, k=8g+e
                oacc[dt] = __builtin_amdgcn_mfma_f32_16x16x32_bf16(va, pb.v, oacc[dt], 0, 0, 0);
            }
        }
    }

    // ---- epilogue: finish l across g-groups, normalize, write O ----
    l_acc += __shfl_xor(l_acc, 16, 64);
    l_acc += __shfl_xor(l_acc, 32, 64);
    const float inv = 1.0f / l_acc;
#pragma unroll
    for (int dt = 0; dt < 4; ++dt)
#pragma unroll
        for (int rg = 0; rg < 4; ++rg)
            O[(size_t)q * DMODEL + h * HD + dt * 16 + g * 4 + rg] = oacc[dt][rg] * inv;
}

// ---------------------------------------------------------------------------
extern "C" void kernel_launch(void* const* d_in, const int* in_sizes, int n_in,
                              void* d_out, int out_size, void* d_ws, size_t ws_size,
                              hipStream_t stream)
{
    const float* x  = (const float*)d_in[0];
    const float* Wq = (const float*)d_in[1];
    const float* Wk = (const float*)d_in[2];
    const float* Wv = (const float*)d_in[3];
    const float* Wo = (const float*)d_in[4];
    float* out = (float*)d_out;

    float* ws = (float*)d_ws;
    const size_t MAT = (size_t)NSEQ * DMODEL;     // 2M floats
    float* Af = ws;                               // Q f32 -> V f32
    float* Bf = ws + MAT;                         // K f32 -> O f32
    unsigned short* Qh = (unsigned short*)(ws + 2 * MAT);
    unsigned short* Ql = Qh + MAT;
    unsigned short* Kh = Ql + MAT;
    unsigned short* Kl = Kh + MAT;
    float* qn = ws + 4 * MAT;
    float* cq = qn + NHEADS * NSEQ;
    float* kn = cq + NHEADS * NSEQ;
    float* ck = kn + NHEADS * NSEQ;

    const dim3 blk(256);
    const dim3 gg(NSEQ / 64, DMODEL / 64);

    gemm_bt_f32<<<gg, blk, 0, stream>>>(x, Wq, Af, NSEQ, DMODEL, DMODEL);
    gemm_bt_f32<<<gg, blk, 0, stream>>>(x, Wk, Bf, NSEQ, DMODEL, DMODEL);

    norms_kernel<<<(2 * NHEADS * NSEQ + 255) / 256, 256, 0, stream>>>(Af, Bf, qn, cq, kn, ck);
    split_qk<<<(int)((MAT / 4 + 255) / 256), 256, 0, stream>>>(Af, Bf, Qh, Ql, Kh, Kl);

    gemm_bt_f32<<<gg, blk, 0, stream>>>(x, Wv, Af, NSEQ, DMODEL, DMODEL);

    // attn reads V f32 from Af, writes O into Bf (K f32 dead after split_qk)
    hyp_attn_simple<<<dim3(NSEQ / 64, NHEADS), blk, 0, stream>>>(
        Qh, Ql, Kh, Kl, Af, qn, cq, kn, ck, Bf);

    gemm_bt_f32<<<gg, blk, 0, stream>>>(Bf, Wo, out, NSEQ, DMODEL, DMODEL);
}

// Round 5
// 166.336 us; speedup vs baseline: 4.9825x; 2.2265x over previous
//
#include <hip/hip_runtime.h>
#include <math.h>

#define NSEQ   2048
#define DMODEL 1024
#define NHEADS 16
#define HD     64

typedef short bf16x8 __attribute__((ext_vector_type(8)));
typedef float f32x4  __attribute__((ext_vector_type(4)));
typedef unsigned short ushort8_t __attribute__((ext_vector_type(8)));

// RTNE float -> bf16 bits
__device__ __forceinline__ unsigned short f2bf(float x) {
    unsigned int u = __builtin_bit_cast(unsigned int, x);
    unsigned int r = (u + 0x7FFFu + ((u >> 16) & 1u)) >> 16;
    return (unsigned short)r;
}
__device__ __forceinline__ float bf2f(unsigned short h) {
    return __builtin_bit_cast(float, (unsigned int)h << 16);
}

// ---------------------------------------------------------------------------
// Convert inputs to bf16: x(2M)->xb, Wq/Wk/Wv(3x1M)->Wb[3072][1024], Wo->Wob.
// 3072 blocks x 256 thr x 8 elems = 6M.
// ---------------------------------------------------------------------------
__global__ __launch_bounds__(256) void convert_inputs(
    const float* __restrict__ x,  const float* __restrict__ Wq,
    const float* __restrict__ Wk, const float* __restrict__ Wv,
    const float* __restrict__ Wo,
    unsigned short* __restrict__ xb, unsigned short* __restrict__ Wb,
    unsigned short* __restrict__ Wob)
{
    const size_t i8 = ((size_t)blockIdx.x * 256 + threadIdx.x) * 8;
    const float* src;
    unsigned short* dst;
    if (i8 < (2ull << 20)) {
        src = x + i8;  dst = xb + i8;
    } else if (i8 < (5ull << 20)) {
        const size_t o = i8 - (2ull << 20);
        const size_t s = o >> 20;
        src = (s == 0 ? Wq : (s == 1 ? Wk : Wv)) + (o & ((1u << 20) - 1));
        dst = Wb + o;
    } else {
        const size_t o = i8 - (5ull << 20);
        src = Wo + o;  dst = Wob + o;
    }
    const float4 v0 = *reinterpret_cast<const float4*>(src);
    const float4 v1 = *reinterpret_cast<const float4*>(src + 4);
    ushort8_t r;
    r[0] = f2bf(v0.x); r[1] = f2bf(v0.y); r[2] = f2bf(v0.z); r[3] = f2bf(v0.w);
    r[4] = f2bf(v1.x); r[5] = f2bf(v1.y); r[6] = f2bf(v1.z); r[7] = f2bf(v1.w);
    *reinterpret_cast<ushort8_t*>(dst) = r;
}

// ---------------------------------------------------------------------------
// bf16 MFMA GEMM (B-transposed): C[m,n] = sum_k A[m,k]*B[n,k], fp32 acc.
// BM=BN=128, BK=64; 256 thr = 4 waves (2x2), wave tile 64x64 (4x4 MFMA tiles).
// Padded LDS rows (72 u16 = 144 B = 9*16B): aligned b128, conflict-free reads.
// Reg-staged (verified pattern; no global_load_lds, no swizzle).
// QKV=1: grid.y spans 3072 cols; cols 0-1023 -> C0 (f32, Q), 1024-2047 -> C1
// (f32, K), 2048-3071 -> C2 (bf16, V). QKV=0: single f32 output C0 (N=1024).
// ---------------------------------------------------------------------------
template <int QKV>
__global__ __launch_bounds__(256) void gemm_bt_bf16(
    const unsigned short* __restrict__ A, const unsigned short* __restrict__ B,
    float* __restrict__ C0, float* __restrict__ C1,
    unsigned short* __restrict__ C2)
{
    __shared__ unsigned short Ahs[128 * 72];
    __shared__ unsigned short Bhs[128 * 72];

    const int bm   = blockIdx.x * 128;
    const int bn   = blockIdx.y * 128;
    const int t    = threadIdx.x;
    const int wid  = t >> 6;
    const int lane = t & 63;
    const int g    = lane >> 4;
    const int r    = lane & 15;
    const int wm   = (wid >> 1) * 64;
    const int wn   = (wid & 1) * 64;

    f32x4 acc[4][4];
#pragma unroll
    for (int i = 0; i < 4; ++i)
#pragma unroll
        for (int j = 0; j < 4; ++j) acc[i][j] = (f32x4){0.f, 0.f, 0.f, 0.f};

    const int srow = t >> 1;         // 0..127
    const int sseg = (t & 1) * 32;   // 0 / 32

    for (int k0 = 0; k0 < DMODEL; k0 += 64) {
        __syncthreads();   // previous tile consumed
        ushort8_t av[4], bv[4];
#pragma unroll
        for (int c = 0; c < 4; ++c) {
            av[c] = *reinterpret_cast<const ushort8_t*>(
                &A[(size_t)(bm + srow) * DMODEL + k0 + sseg + c * 8]);
            bv[c] = *reinterpret_cast<const ushort8_t*>(
                &B[(size_t)(bn + srow) * DMODEL + k0 + sseg + c * 8]);
        }
#pragma unroll
        for (int c = 0; c < 4; ++c) {
            *reinterpret_cast<ushort8_t*>(&Ahs[srow * 72 + sseg + c * 8]) = av[c];
            *reinterpret_cast<ushort8_t*>(&Bhs[srow * 72 + sseg + c * 8]) = bv[c];
        }
        __syncthreads();

#pragma unroll
        for (int dc = 0; dc < 2; ++dc) {
            bf16x8 af[4], bfr[4];
#pragma unroll
            for (int mt = 0; mt < 4; ++mt)
                af[mt] = *reinterpret_cast<const bf16x8*>(
                    &Ahs[(wm + mt * 16 + r) * 72 + dc * 32 + g * 8]);
#pragma unroll
            for (int nt = 0; nt < 4; ++nt)
                bfr[nt] = *reinterpret_cast<const bf16x8*>(
                    &Bhs[(wn + nt * 16 + r) * 72 + dc * 32 + g * 8]);
#pragma unroll
            for (int mt = 0; mt < 4; ++mt)
#pragma unroll
                for (int nt = 0; nt < 4; ++nt)
                    acc[mt][nt] = __builtin_amdgcn_mfma_f32_16x16x32_bf16(
                        af[mt], bfr[nt], acc[mt][nt], 0, 0, 0);
        }
    }

    // epilogue: D row = (l>>4)*4+rg -> m; col = l&15 -> n  (verified mapping)
    if (QKV) {
        const int sel = bn >> 10;
        const int bnl = bn & 1023;
        if (sel < 2) {
            float* Cf = sel ? C1 : C0;
#pragma unroll
            for (int mt = 0; mt < 4; ++mt)
#pragma unroll
                for (int nt = 0; nt < 4; ++nt)
#pragma unroll
                    for (int rg = 0; rg < 4; ++rg)
                        Cf[(size_t)(bm + wm + mt * 16 + g * 4 + rg) * 1024 +
                           bnl + wn + nt * 16 + r] = acc[mt][nt][rg];
        } else {
#pragma unroll
            for (int mt = 0; mt < 4; ++mt)
#pragma unroll
                for (int nt = 0; nt < 4; ++nt)
#pragma unroll
                    for (int rg = 0; rg < 4; ++rg)
                        C2[(size_t)(bm + wm + mt * 16 + g * 4 + rg) * 1024 +
                           bnl + wn + nt * 16 + r] = f2bf(acc[mt][nt][rg]);
        }
    } else {
#pragma unroll
        for (int mt = 0; mt < 4; ++mt)
#pragma unroll
            for (int nt = 0; nt < 4; ++nt)
#pragma unroll
                for (int rg = 0; rg < 4; ++rg)
                    C0[(size_t)(bm + wm + mt * 16 + g * 4 + rg) * 1024 +
                       bn + wn + nt * 16 + r] = acc[mt][nt][rg];
    }
}

// ---------------------------------------------------------------------------
// Per-head norms + reciprocals: qn, cq=1/(1-qn); kn, ck=1/(1-kn).
// ---------------------------------------------------------------------------
__global__ void norms_kernel(const float* __restrict__ Q,
                             const float* __restrict__ K,
                             float* __restrict__ qn, float* __restrict__ cq,
                             float* __restrict__ kn, float* __restrict__ ck)
{
    const int idx   = blockIdx.x * blockDim.x + threadIdx.x;
    const int total = NHEADS * NSEQ;
    if (idx >= 2 * total) return;
    const bool isK = idx >= total;
    const int  r   = isK ? idx - total : idx;
    const int  h   = r >> 11;
    const int  n   = r & (NSEQ - 1);
    const float* src = (isK ? K : Q) + (size_t)n * DMODEL + h * HD;
    float s = 0.f;
#pragma unroll
    for (int d = 0; d < HD; d += 4) {
        const float4 v = *reinterpret_cast<const float4*>(&src[d]);
        s = fmaf(v.x, v.x, s); s = fmaf(v.y, v.y, s);
        s = fmaf(v.z, v.z, s); s = fmaf(v.w, v.w, s);
    }
    (isK ? kn : qn)[r] = s;
    (isK ? ck : cq)[r] = 1.0f / (1.0f - s);
}

// ---------------------------------------------------------------------------
// MFMA hyperbolic attention (verified R4 structure; in-kernel hi/lo split).
// Q,K read as fp32 and split to bf16 hi/lo during staging (replaces split_qk);
// V read as bf16 (written by the QKV GEMM); O written as bf16 for the final
// GEMM. All LDS layouts/indices identical to the R4-passing kernel.
// ---------------------------------------------------------------------------
__global__ __launch_bounds__(256) void hyp_attn_simple(
    const float* __restrict__ Qf, const float* __restrict__ Kf,
    const unsigned short* __restrict__ Vb,
    const float* __restrict__ qn_a, const float* __restrict__ cq_a,
    const float* __restrict__ kn_a, const float* __restrict__ ck_a,
    unsigned short* __restrict__ Ob)
{
    __shared__ unsigned short Khs[64 * 72];     // [j][d] hi, pad 8
    __shared__ unsigned short Kls[64 * 72];     // [j][d] lo
    __shared__ unsigned short Vts[64 * 72];     // [d][j] (V^T)
    __shared__ unsigned short PsB[4 * 64 * 24]; // per-wave [j][q], pad 8
    __shared__ float kns[64];
    __shared__ float cks[64];

    const int h    = blockIdx.y;
    const int n0   = blockIdx.x * 64;
    const int t    = threadIdx.x;
    const int wid  = t >> 6;
    const int lane = t & 63;
    const int g    = lane >> 4;
    const int r    = lane & 15;
    const int q    = n0 + wid * 16 + r;

    // Q fragments: fp32 -> hi/lo bf16 in-register (same values as split_qk)
    bf16x8 qfh[2], qfl[2];
#pragma unroll
    for (int dc = 0; dc < 2; ++dc) {
        const float* qsrc = Qf + (size_t)q * DMODEL + h * HD + dc * 32 + g * 8;
        const float4 f0 = *reinterpret_cast<const float4*>(qsrc);
        const float4 f1 = *reinterpret_cast<const float4*>(qsrc + 4);
        const float fv[8] = {f0.x, f0.y, f0.z, f0.w, f1.x, f1.y, f1.z, f1.w};
        union { unsigned short s[8]; bf16x8 v; } uh, ul;
#pragma unroll
        for (int e = 0; e < 8; ++e) {
            const unsigned short hb = f2bf(fv[e]);
            uh.s[e] = hb;
            ul.s[e] = f2bf(fv[e] - bf2f(hb));
        }
        qfh[dc] = uh.v;
        qfl[dc] = ul.v;
    }
    const float qn_l = qn_a[h * NSEQ + q];
    const float cq2  = 2.0f * cq_a[h * NSEQ + q];

    unsigned short* Pw = PsB + wid * (64 * 24);

    f32x4 oacc[4];
#pragma unroll
    for (int dt = 0; dt < 4; ++dt) oacc[dt] = (f32x4){0.f, 0.f, 0.f, 0.f};
    float l_acc = 0.f;

    for (int jb = 0; jb < NSEQ / 64; ++jb) {
        const int j0 = jb * 64;
        __syncthreads();   // previous tile fully consumed by all waves

        // ---- stage K hi/lo ([j][d], split from fp32) and V^T ([d][j]) ----
        {
            const int j  = t >> 2;
            const int dq = (t & 3) * 16;
            const float* ksrc = Kf + (size_t)(j0 + j) * DMODEL + h * HD + dq;
            union { unsigned short s[16]; ushort8_t v[2]; } khv, klv;
#pragma unroll
            for (int c = 0; c < 16; c += 4) {
                const float4 kv = *reinterpret_cast<const float4*>(ksrc + c);
                const float ka[4] = {kv.x, kv.y, kv.z, kv.w};
#pragma unroll
                for (int e = 0; e < 4; ++e) {
                    const unsigned short hb = f2bf(ka[e]);
                    khv.s[c + e] = hb;
                    klv.s[c + e] = f2bf(ka[e] - bf2f(hb));
                }
            }
            *reinterpret_cast<ushort8_t*>(&Khs[j * 72 + dq])     = khv.v[0];
            *reinterpret_cast<ushort8_t*>(&Khs[j * 72 + dq + 8]) = khv.v[1];
            *reinterpret_cast<ushort8_t*>(&Kls[j * 72 + dq])     = klv.v[0];
            *reinterpret_cast<ushort8_t*>(&Kls[j * 72 + dq + 8]) = klv.v[1];

            const ushort8_t v0 = *reinterpret_cast<const ushort8_t*>(
                &Vb[(size_t)(j0 + j) * DMODEL + h * HD + dq]);
            const ushort8_t v1 = *reinterpret_cast<const ushort8_t*>(
                &Vb[(size_t)(j0 + j) * DMODEL + h * HD + dq + 8]);
#pragma unroll
            for (int c = 0; c < 8; ++c) {
                Vts[(dq + c) * 72 + j]     = v0[c];
                Vts[(dq + 8 + c) * 72 + j] = v1[c];
            }
            if (t < 64)       kns[t]      = kn_a[h * NSEQ + j0 + t];
            else if (t < 128) cks[t - 64] = ck_a[h * NSEQ + j0 + t - 64];
        }
        __syncthreads();

        // ---- S^T tiles + distance -> P (bf16, wave-private LDS) ----
#pragma unroll
        for (int jt = 0; jt < 4; ++jt) {
            f32x4 sac = (f32x4){0.f, 0.f, 0.f, 0.f};
#pragma unroll
            for (int dc = 0; dc < 2; ++dc) {
                const int row = jt * 16 + r;
                const bf16x8 kh = *reinterpret_cast<const bf16x8*>(
                    &Khs[row * 72 + dc * 32 + g * 8]);
                const bf16x8 kl = *reinterpret_cast<const bf16x8*>(
                    &Kls[row * 72 + dc * 32 + g * 8]);
                sac = __builtin_amdgcn_mfma_f32_16x16x32_bf16(kh, qfh[dc], sac, 0, 0, 0);
                sac = __builtin_amdgcn_mfma_f32_16x16x32_bf16(kh, qfl[dc], sac, 0, 0, 0);
                sac = __builtin_amdgcn_mfma_f32_16x16x32_bf16(kl, qfh[dc], sac, 0, 0, 0);
            }
#pragma unroll
            for (int rg = 0; rg < 4; ++rg) {
                const int jl = jt * 16 + g * 4 + rg;   // D-map: row=(l>>4)*4+reg
                const float kn_v = kns[jl];
                const float ck_v = cks[jl];
                const float qk  = sac[rg];
                const float dsq = fmaxf(fmaf(-2.f, qk, qn_l + kn_v), 0.f);
                const float ca  = fmaxf(fmaf(dsq, cq2 * ck_v, 1.f), 1.0f);
                const float s2  = fmaxf(fmaf(ca, ca, -1.f), 0.f);
                const float wj  = __builtin_amdgcn_rcpf(ca + __builtin_amdgcn_sqrtf(s2));
                l_acc += wj;
                Pw[jl * 24 + r] = f2bf(wj);            // P[j][q], q = r (D-map col)
            }
        }
        // Pw is wave-private: within-wave ds_write->ds_read ordering suffices.

        // ---- PV: O^T += V^T * P ----
#pragma unroll
        for (int kc = 0; kc < 2; ++kc) {
            union { unsigned short s[8]; bf16x8 v; } pb;
#pragma unroll
            for (int e = 0; e < 8; ++e)
                pb.s[e] = Pw[(kc * 32 + g * 8 + e) * 24 + r];  // B: k=8g+e, n=r
#pragma unroll
            for (int dt = 0; dt < 4; ++dt) {
                const bf16x8 va = *reinterpret_cast<const bf16x8*>(
                    &Vts[(dt * 16 + r) * 72 + kc * 32 + g * 8]); // A: m=r, k=8g+e
                oacc[dt] = __builtin_amdgcn_mfma_f32_16x16x32_bf16(va, pb.v, oacc[dt], 0, 0, 0);
            }
        }
    }

    // ---- epilogue: finish l, normalize, write O as bf16 ----
    l_acc += __shfl_xor(l_acc, 16, 64);
    l_acc += __shfl_xor(l_acc, 32, 64);
    const float inv = 1.0f / l_acc;
#pragma unroll
    for (int dt = 0; dt < 4; ++dt) {
        ushort4 o4;
        o4.x = f2bf(oacc[dt][0] * inv);
        o4.y = f2bf(oacc[dt][1] * inv);
        o4.z = f2bf(oacc[dt][2] * inv);
        o4.w = f2bf(oacc[dt][3] * inv);
        *reinterpret_cast<ushort4*>(
            &Ob[(size_t)q * DMODEL + h * HD + dt * 16 + g * 4]) = o4;
    }
}

// ---------------------------------------------------------------------------
extern "C" void kernel_launch(void* const* d_in, const int* in_sizes, int n_in,
                              void* d_out, int out_size, void* d_ws, size_t ws_size,
                              hipStream_t stream)
{
    const float* x  = (const float*)d_in[0];
    const float* Wq = (const float*)d_in[1];
    const float* Wk = (const float*)d_in[2];
    const float* Wv = (const float*)d_in[3];
    const float* Wo = (const float*)d_in[4];
    float* out = (float*)d_out;

    char* ws = (char*)d_ws;
    const size_t MAT = (size_t)NSEQ * DMODEL;            // 2M elements
    float*          Qf  = (float*)ws;                    //  8 MB
    float*          Kf  = (float*)(ws + 8  * 1048576);   //  8 MB
    unsigned short* Vb  = (unsigned short*)(ws + 16 * 1048576);  // 4 MB
    unsigned short* xb  = (unsigned short*)(ws + 20 * 1048576);  // 4 MB (-> Ob)
    unsigned short* Wb  = (unsigned short*)(ws + 24 * 1048576);  // 6 MB
    unsigned short* Wob = (unsigned short*)(ws + 30 * 1048576);  // 2 MB
    float*          qn  = (float*)(ws + 32 * 1048576);
    float*          cq  = qn + NHEADS * NSEQ;
    float*          kn  = cq + NHEADS * NSEQ;
    float*          ck  = kn + NHEADS * NSEQ;
    unsigned short* Ob  = xb;   // xb dead after QKV GEMM; reuse for O (bf16)

    const dim3 blk(256);

    // 1. fp32 -> bf16 conversions (x, Wq|Wk|Wv concat, Wo)
    convert_inputs<<<3072, blk, 0, stream>>>(x, Wq, Wk, Wv, Wo, xb, Wb, Wob);

    // 2. fused QKV projection: xb . Wb^T  ->  Qf (f32), Kf (f32), Vb (bf16)
    gemm_bt_bf16<1><<<dim3(NSEQ / 128, 3072 / 128), blk, 0, stream>>>(
        xb, Wb, Qf, Kf, Vb);

    // 3. per-head norms from fp32 Q,K
    norms_kernel<<<(2 * NHEADS * NSEQ + 255) / 256, blk, 0, stream>>>(
        Qf, Kf, qn, cq, kn, ck);

    // 4. fused hyperbolic attention -> Ob (bf16)
    hyp_attn_simple<<<dim3(NSEQ / 64, NHEADS), blk, 0, stream>>>(
        Qf, Kf, Vb, qn, cq, kn, ck, Ob);

    // 5. output projection: Ob . Wob^T -> out (f32)
    gemm_bt_bf16<0><<<dim3(NSEQ / 128, DMODEL / 128), blk, 0, stream>>>(
        Ob, Wob, out, nullptr, nullptr);
}

// Round 6
// 138.753 us; speedup vs baseline: 5.9729x; 1.1988x over previous
//
#include <hip/hip_runtime.h>
#include <math.h>

#define NSEQ   2048
#define DMODEL 1024
#define NHEADS 16
#define HD     64

typedef short bf16x8 __attribute__((ext_vector_type(8)));
typedef float f32x4  __attribute__((ext_vector_type(4)));
typedef unsigned short ushort8_t __attribute__((ext_vector_type(8)));

// RTNE float -> bf16 bits
__device__ __forceinline__ unsigned short f2bf(float x) {
    unsigned int u = __builtin_bit_cast(unsigned int, x);
    unsigned int r = (u + 0x7FFFu + ((u >> 16) & 1u)) >> 16;
    return (unsigned short)r;
}
__device__ __forceinline__ float bf2f(unsigned short h) {
    return __builtin_bit_cast(float, (unsigned int)h << 16);
}

// ---------------------------------------------------------------------------
// Convert inputs to bf16: x(2M)->xb, Wq/Wk/Wv(3x1M)->Wb[3072][1024], Wo->Wob.
// ---------------------------------------------------------------------------
__global__ __launch_bounds__(256) void convert_inputs(
    const float* __restrict__ x,  const float* __restrict__ Wq,
    const float* __restrict__ Wk, const float* __restrict__ Wv,
    const float* __restrict__ Wo,
    unsigned short* __restrict__ xb, unsigned short* __restrict__ Wb,
    unsigned short* __restrict__ Wob)
{
    const size_t i8 = ((size_t)blockIdx.x * 256 + threadIdx.x) * 8;
    const float* src;
    unsigned short* dst;
    if (i8 < (2ull << 20)) {
        src = x + i8;  dst = xb + i8;
    } else if (i8 < (5ull << 20)) {
        const size_t o = i8 - (2ull << 20);
        const size_t s = o >> 20;
        src = (s == 0 ? Wq : (s == 1 ? Wk : Wv)) + (o & ((1u << 20) - 1));
        dst = Wb + o;
    } else {
        const size_t o = i8 - (5ull << 20);
        src = Wo + o;  dst = Wob + o;
    }
    const float4 v0 = *reinterpret_cast<const float4*>(src);
    const float4 v1 = *reinterpret_cast<const float4*>(src + 4);
    ushort8_t r;
    r[0] = f2bf(v0.x); r[1] = f2bf(v0.y); r[2] = f2bf(v0.z); r[3] = f2bf(v0.w);
    r[4] = f2bf(v1.x); r[5] = f2bf(v1.y); r[6] = f2bf(v1.z); r[7] = f2bf(v1.w);
    *reinterpret_cast<ushort8_t*>(dst) = r;
}

// ---------------------------------------------------------------------------
// bf16 MFMA GEMM (B-transposed): C[m,n] = sum_k A[m,k]*B[n,k], fp32 acc.
// BM=BN=128, BK=64; 4 waves (2x2), wave tile 64x64. Padded-72 LDS rows.
// QKV=1 epilogue (verified core, extended):
//   cols 0-1023   (Q): write hi/lo bf16 split + per-(head,row) qn, cq2=2/(1-qn)
//   cols 1024-2047(K): write hi/lo bf16 split + kn, ck=1/(1-kn)
//   cols 2048-3071(V): write bf16
// Norm reduction: each wave's 64 cols = exactly one head; row m = g*4+rg lives
// in the 16 r-lanes (cols nt*16+r) -> shfl_xor(1,2,4,8) completes sum(q^2).
// QKV=0: plain f32 output C0 (N=1024).
// ---------------------------------------------------------------------------
template <int QKV>
__global__ __launch_bounds__(256) void gemm_bt_bf16(
    const unsigned short* __restrict__ A, const unsigned short* __restrict__ B,
    float* __restrict__ C0,
    unsigned short* __restrict__ QhO, unsigned short* __restrict__ QlO,
    float* __restrict__ qnO, float* __restrict__ cq2O,
    unsigned short* __restrict__ KhO, unsigned short* __restrict__ KlO,
    float* __restrict__ knO, float* __restrict__ ckO,
    unsigned short* __restrict__ VbO)
{
    __shared__ unsigned short Ahs[128 * 72];
    __shared__ unsigned short Bhs[128 * 72];

    const int bm   = blockIdx.x * 128;
    const int bn   = blockIdx.y * 128;
    const int t    = threadIdx.x;
    const int wid  = t >> 6;
    const int lane = t & 63;
    const int g    = lane >> 4;
    const int r    = lane & 15;
    const int wm   = (wid >> 1) * 64;
    const int wn   = (wid & 1) * 64;

    f32x4 acc[4][4];
#pragma unroll
    for (int i = 0; i < 4; ++i)
#pragma unroll
        for (int j = 0; j < 4; ++j) acc[i][j] = (f32x4){0.f, 0.f, 0.f, 0.f};

    const int srow = t >> 1;
    const int sseg = (t & 1) * 32;

    for (int k0 = 0; k0 < DMODEL; k0 += 64) {
        __syncthreads();
        ushort8_t av[4], bv[4];
#pragma unroll
        for (int c = 0; c < 4; ++c) {
            av[c] = *reinterpret_cast<const ushort8_t*>(
                &A[(size_t)(bm + srow) * DMODEL + k0 + sseg + c * 8]);
            bv[c] = *reinterpret_cast<const ushort8_t*>(
                &B[(size_t)(bn + srow) * DMODEL + k0 + sseg + c * 8]);
        }
#pragma unroll
        for (int c = 0; c < 4; ++c) {
            *reinterpret_cast<ushort8_t*>(&Ahs[srow * 72 + sseg + c * 8]) = av[c];
            *reinterpret_cast<ushort8_t*>(&Bhs[srow * 72 + sseg + c * 8]) = bv[c];
        }
        __syncthreads();

#pragma unroll
        for (int dc = 0; dc < 2; ++dc) {
            bf16x8 af[4], bfr[4];
#pragma unroll
            for (int mt = 0; mt < 4; ++mt)
                af[mt] = *reinterpret_cast<const bf16x8*>(
                    &Ahs[(wm + mt * 16 + r) * 72 + dc * 32 + g * 8]);
#pragma unroll
            for (int nt = 0; nt < 4; ++nt)
                bfr[nt] = *reinterpret_cast<const bf16x8*>(
                    &Bhs[(wn + nt * 16 + r) * 72 + dc * 32 + g * 8]);
#pragma unroll
            for (int mt = 0; mt < 4; ++mt)
#pragma unroll
                for (int nt = 0; nt < 4; ++nt)
                    acc[mt][nt] = __builtin_amdgcn_mfma_f32_16x16x32_bf16(
                        af[mt], bfr[nt], acc[mt][nt], 0, 0, 0);
        }
    }

    if (QKV) {
        const int sel = bn >> 10;
        const int bnl = bn & 1023;
        if (sel < 2) {
            unsigned short* Hh = sel ? KhO : QhO;
            unsigned short* Hl = sel ? KlO : QlO;
            float* narr = sel ? knO  : qnO;
            float* carr = sel ? ckO  : cq2O;
            const int hh = (bnl + wn) >> 6;   // one head per wave (64 cols)
#pragma unroll
            for (int mt = 0; mt < 4; ++mt) {
#pragma unroll
                for (int rg = 0; rg < 4; ++rg) {
                    float ss = 0.f;
#pragma unroll
                    for (int nt = 0; nt < 4; ++nt) {
                        const float v = acc[mt][nt][rg];
                        ss = fmaf(v, v, ss);
                        const unsigned short hb = f2bf(v);
                        const size_t idx =
                            (size_t)(bm + wm + mt * 16 + g * 4 + rg) * 1024 +
                            bnl + wn + nt * 16 + r;
                        Hh[idx] = hb;
                        Hl[idx] = f2bf(v - bf2f(hb));
                    }
                    ss += __shfl_xor(ss, 1, 64);
                    ss += __shfl_xor(ss, 2, 64);
                    ss += __shfl_xor(ss, 4, 64);
                    ss += __shfl_xor(ss, 8, 64);
                    if (r == 0) {
                        const int row = bm + wm + mt * 16 + g * 4 + rg;
                        narr[hh * NSEQ + row] = ss;
                        carr[hh * NSEQ + row] =
                            (sel ? 1.0f : 2.0f) / (1.0f - ss);
                    }
                }
            }
        } else {
#pragma unroll
            for (int mt = 0; mt < 4; ++mt)
#pragma unroll
                for (int nt = 0; nt < 4; ++nt)
#pragma unroll
                    for (int rg = 0; rg < 4; ++rg)
                        VbO[(size_t)(bm + wm + mt * 16 + g * 4 + rg) * 1024 +
                            bnl + wn + nt * 16 + r] = f2bf(acc[mt][nt][rg]);
        }
    } else {
#pragma unroll
        for (int mt = 0; mt < 4; ++mt)
#pragma unroll
            for (int nt = 0; nt < 4; ++nt)
#pragma unroll
                for (int rg = 0; rg < 4; ++rg)
                    C0[(size_t)(bm + wm + mt * 16 + g * 4 + rg) * 1024 +
                       bn + wn + nt * 16 + r] = acc[mt][nt][rg];
    }
}

// ---------------------------------------------------------------------------
// Per-head V transpose (bf16->bf16): Vt[(h*64+d)*2048 + n] = Vb[n*1024+h*64+d]
// ---------------------------------------------------------------------------
__global__ __launch_bounds__(256) void vt_kernel_bf16(
    const unsigned short* __restrict__ Vb, unsigned short* __restrict__ Vt)
{
    __shared__ unsigned short Vs[64 * 72];
    const int h   = blockIdx.y;
    const int n0  = blockIdx.x * 64;
    const int t   = threadIdx.x;
    const int row = t >> 2;
    const int seg = (t & 3) * 16;

    const unsigned short* src = Vb + (size_t)(n0 + row) * 1024 + h * HD + seg;
    *reinterpret_cast<ushort8_t*>(&Vs[row * 72 + seg]) =
        *reinterpret_cast<const ushort8_t*>(src);
    *reinterpret_cast<ushort8_t*>(&Vs[row * 72 + seg + 8]) =
        *reinterpret_cast<const ushort8_t*>(src + 8);
    __syncthreads();

    ushort8_t a, b;
#pragma unroll
    for (int c = 0; c < 8; ++c) a[c] = Vs[(seg + c) * 72 + row];
#pragma unroll
    for (int c = 0; c < 8; ++c) b[c] = Vs[(seg + 8 + c) * 72 + row];
    unsigned short* dst = Vt + (size_t)(h * HD + row) * NSEQ + n0 + seg;
    *reinterpret_cast<ushort8_t*>(dst)     = a;
    *reinterpret_cast<ushort8_t*>(dst + 8) = b;
}

// ---------------------------------------------------------------------------
// MFMA hyperbolic attention v2 (non-swapped orientation, j-split partials).
// Grid (NSEQ/64, NHEADS, 2). 256 thr = 4 waves; wave w: q rows [n0+16w,+16).
// Fragment maps (verified conventions from the passing GEMM/R4 kernels):
//   A-frag: m=r, k=g*8+e.  B-frag: n=r, k=g*8+e.  D: row(m)=g*4+rg, col(n)=r.
// S  = mfma(Qfrag, Kfrag): thread holds S[q=g*4+rg][j=16jt+r].
// PV = mfma(Pfrag, Vfrag): P A-frag = P[q=r][j=kc*32+g*8+e] -> VECTOR LDS read
//   from wave-private Ps rows (stride 68 u16: write bank-bases 8g+2rg mod 32,
//   disjoint; read balanced). V B-frag = Vt rows (vector).
// Weights: w = ca - sqrt(ca^2-1)  (== exp(-acosh(ca)), no rcp, no cancellation
// for ca in [1,~1.6]). No max-tracking needed since w<=1. Partial O (f32) and
// partial l per j-half; merged by merge_kernel (no rescale needed).
// ---------------------------------------------------------------------------
__global__ __launch_bounds__(256) void hyp_attn_v2(
    const unsigned short* __restrict__ Qh, const unsigned short* __restrict__ Ql,
    const unsigned short* __restrict__ Kh, const unsigned short* __restrict__ Kl,
    const unsigned short* __restrict__ Vt,
    const float* __restrict__ qn_a, const float* __restrict__ cq2_a,
    const float* __restrict__ kn_a, const float* __restrict__ ck_a,
    float* __restrict__ Opart, float* __restrict__ lpart)
{
    __shared__ unsigned short Khs[64 * 72];
    __shared__ unsigned short Kls[64 * 72];
    __shared__ unsigned short Vts[64 * 72];
    __shared__ unsigned short Ps[4][16 * 68];
    __shared__ float kns[64];
    __shared__ float cks[64];

    const int h    = blockIdx.y;
    const int n0   = blockIdx.x * 64;
    const int jh   = blockIdx.z;
    const int t    = threadIdx.x;
    const int wid  = t >> 6;
    const int lane = t & 63;
    const int g    = lane >> 4;
    const int r    = lane & 15;
    const int qb   = n0 + wid * 16;

    // Q A-frags (hi/lo): Q[qb+r][k = dc*32 + g*8 + e]
    bf16x8 qfh[2], qfl[2];
#pragma unroll
    for (int dc = 0; dc < 2; ++dc) {
        const size_t off = (size_t)(qb + r) * DMODEL + h * HD + dc * 32 + g * 8;
        qfh[dc] = *reinterpret_cast<const bf16x8*>(Qh + off);
        qfl[dc] = *reinterpret_cast<const bf16x8*>(Ql + off);
    }
    // per-q constants for the 4 D-rows this thread owns (q = qb + g*4 + rg)
    float qn_r[4], c2q[4];
#pragma unroll
    for (int rg = 0; rg < 4; ++rg) {
        qn_r[rg] = qn_a[h * NSEQ + qb + g * 4 + rg];
        c2q[rg]  = cq2_a[h * NSEQ + qb + g * 4 + rg];
    }

    f32x4 oacc[4];
#pragma unroll
    for (int nt = 0; nt < 4; ++nt) oacc[nt] = (f32x4){0.f, 0.f, 0.f, 0.f};
    float l_acc[4] = {0.f, 0.f, 0.f, 0.f};

    const int srow = t >> 2;
    const int sseg = (t & 3) * 16;
    unsigned short* Pw = &Ps[wid][0];

    for (int tb = 0; tb < 16; ++tb) {
        const int j0 = jh * 1024 + tb * 64;
        __syncthreads();
        // ---- stage (pure vector copies) ----
        {
            const unsigned short* ks = Kh + (size_t)(j0 + srow) * DMODEL + h * HD + sseg;
            const unsigned short* ls = Kl + (size_t)(j0 + srow) * DMODEL + h * HD + sseg;
            const unsigned short* vs = Vt + (size_t)(h * HD + srow) * NSEQ + j0 + sseg;
            *reinterpret_cast<ushort8_t*>(&Khs[srow * 72 + sseg]) =
                *reinterpret_cast<const ushort8_t*>(ks);
            *reinterpret_cast<ushort8_t*>(&Khs[srow * 72 + sseg + 8]) =
                *reinterpret_cast<const ushort8_t*>(ks + 8);
            *reinterpret_cast<ushort8_t*>(&Kls[srow * 72 + sseg]) =
                *reinterpret_cast<const ushort8_t*>(ls);
            *reinterpret_cast<ushort8_t*>(&Kls[srow * 72 + sseg + 8]) =
                *reinterpret_cast<const ushort8_t*>(ls + 8);
            *reinterpret_cast<ushort8_t*>(&Vts[srow * 72 + sseg]) =
                *reinterpret_cast<const ushort8_t*>(vs);
            *reinterpret_cast<ushort8_t*>(&Vts[srow * 72 + sseg + 8]) =
                *reinterpret_cast<const ushort8_t*>(vs + 8);
            if (t < 64)       kns[t]      = kn_a[h * NSEQ + j0 + t];
            else if (t < 128) cks[t - 64] = ck_a[h * NSEQ + j0 + t - 64];
        }
        __syncthreads();

        // ---- S tiles + distance -> w ----
        float w[4][4];   // [jt][rg]
#pragma unroll
        for (int jt = 0; jt < 4; ++jt) {
            f32x4 sac = (f32x4){0.f, 0.f, 0.f, 0.f};
#pragma unroll
            for (int dc = 0; dc < 2; ++dc) {
                const bf16x8 kb = *reinterpret_cast<const bf16x8*>(
                    &Khs[(jt * 16 + r) * 72 + dc * 32 + g * 8]);
                const bf16x8 lb = *reinterpret_cast<const bf16x8*>(
                    &Kls[(jt * 16 + r) * 72 + dc * 32 + g * 8]);
                sac = __builtin_amdgcn_mfma_f32_16x16x32_bf16(qfh[dc], kb, sac, 0, 0, 0);
                sac = __builtin_amdgcn_mfma_f32_16x16x32_bf16(qfl[dc], kb, sac, 0, 0, 0);
                sac = __builtin_amdgcn_mfma_f32_16x16x32_bf16(qfh[dc], lb, sac, 0, 0, 0);
            }
            const float kn_v = kns[jt * 16 + r];
            const float ck_v = cks[jt * 16 + r];
#pragma unroll
            for (int rg = 0; rg < 4; ++rg) {
                const float qk  = sac[rg];
                const float dsq = fmaxf(fmaf(-2.f, qk, qn_r[rg] + kn_v), 0.f);
                const float ca  = fmaxf(fmaf(dsq, c2q[rg] * ck_v, 1.f), 1.0f);
                const float s2  = fmaxf(fmaf(ca, ca, -1.f), 0.f);
                const float wj  = ca - __builtin_amdgcn_sqrtf(s2);
                l_acc[rg] += wj;
                w[jt][rg] = wj;
            }
        }

        // ---- P -> wave-private LDS (row = q-local = g*4+rg, col = 16jt+r) ----
#pragma unroll
        for (int jt = 0; jt < 4; ++jt)
#pragma unroll
            for (int rg = 0; rg < 4; ++rg)
                Pw[(g * 4 + rg) * 68 + jt * 16 + r] = f2bf(w[jt][rg]);
        // wave-private: within-wave ds ordering suffices (verified pattern)

        // ---- PV: O[q][d] += P . V ----
#pragma unroll
        for (int kc = 0; kc < 2; ++kc) {
            const bf16x8 pa = *reinterpret_cast<const bf16x8*>(
                &Pw[r * 68 + kc * 32 + g * 8]);            // A: m=r(q), k=j
#pragma unroll
            for (int nt = 0; nt < 4; ++nt) {
                const bf16x8 vb = *reinterpret_cast<const bf16x8*>(
                    &Vts[(nt * 16 + r) * 72 + kc * 32 + g * 8]); // B: n=r(d), k=j
                oacc[nt] = __builtin_amdgcn_mfma_f32_16x16x32_bf16(pa, vb, oacc[nt], 0, 0, 0);
            }
        }
    }

    // ---- l reduce over the 16 r-lanes (j = 16jt + r spans all j) ----
#pragma unroll
    for (int rg = 0; rg < 4; ++rg) {
        l_acc[rg] += __shfl_xor(l_acc[rg], 1, 64);
        l_acc[rg] += __shfl_xor(l_acc[rg], 2, 64);
        l_acc[rg] += __shfl_xor(l_acc[rg], 4, 64);
        l_acc[rg] += __shfl_xor(l_acc[rg], 8, 64);
    }

    // ---- write partials ----
    float* Op = Opart + (size_t)jh * NSEQ * DMODEL;
#pragma unroll
    for (int nt = 0; nt < 4; ++nt)
#pragma unroll
        for (int rg = 0; rg < 4; ++rg)
            Op[(size_t)(qb + g * 4 + rg) * DMODEL + h * HD + nt * 16 + r] =
                oacc[nt][rg];
    if (r == 0) {
#pragma unroll
        for (int rg = 0; rg < 4; ++rg)
            lpart[(jh * NHEADS + h) * NSEQ + qb + g * 4 + rg] = l_acc[rg];
    }
}

// ---------------------------------------------------------------------------
// Merge j-split partials: Ob = bf16((O0+O1) / (l0+l1)).
// ---------------------------------------------------------------------------
__global__ __launch_bounds__(256) void merge_kernel(
    const float* __restrict__ Opart, const float* __restrict__ lpart,
    unsigned short* __restrict__ Ob)
{
    const size_t i8 = ((size_t)blockIdx.x * 256 + threadIdx.x) * 8;
    if (i8 >= (size_t)NSEQ * DMODEL) return;
    const int n  = (int)(i8 >> 10);
    const int dm = (int)(i8 & 1023);
    const int h  = dm >> 6;
    const float li = 1.0f / (lpart[h * NSEQ + n] +
                             lpart[(NHEADS + h) * NSEQ + n]);
    const float* O0 = Opart + i8;
    const float* O1 = Opart + (size_t)NSEQ * DMODEL + i8;
    ushort8_t o;
#pragma unroll
    for (int c = 0; c < 2; ++c) {
        const float4 a = *reinterpret_cast<const float4*>(O0 + c * 4);
        const float4 b = *reinterpret_cast<const float4*>(O1 + c * 4);
        o[c * 4 + 0] = f2bf((a.x + b.x) * li);
        o[c * 4 + 1] = f2bf((a.y + b.y) * li);
        o[c * 4 + 2] = f2bf((a.z + b.z) * li);
        o[c * 4 + 3] = f2bf((a.w + b.w) * li);
    }
    *reinterpret_cast<ushort8_t*>(Ob + i8) = o;
}

// ---------------------------------------------------------------------------
extern "C" void kernel_launch(void* const* d_in, const int* in_sizes, int n_in,
                              void* d_out, int out_size, void* d_ws, size_t ws_size,
                              hipStream_t stream)
{
    const float* x  = (const float*)d_in[0];
    const float* Wq = (const float*)d_in[1];
    const float* Wk = (const float*)d_in[2];
    const float* Wv = (const float*)d_in[3];
    const float* Wo = (const float*)d_in[4];
    float* out = (float*)d_out;

    char* ws = (char*)d_ws;
    const size_t MB = 1048576;
    unsigned short* xb   = (unsigned short*)(ws);             // 4MB (-> Ob)
    unsigned short* Wb   = (unsigned short*)(ws + 4  * MB);   // 6MB
    unsigned short* Wob  = (unsigned short*)(ws + 10 * MB);   // 2MB
    unsigned short* Qh   = (unsigned short*)(ws + 12 * MB);   // 4MB
    unsigned short* Ql   = (unsigned short*)(ws + 16 * MB);   // 4MB
    unsigned short* Kh   = (unsigned short*)(ws + 20 * MB);   // 4MB
    unsigned short* Kl   = (unsigned short*)(ws + 24 * MB);   // 4MB
    unsigned short* Vb   = (unsigned short*)(ws + 28 * MB);   // 4MB
    unsigned short* Vt   = (unsigned short*)(ws + 32 * MB);   // 4MB
    float*          qn   = (float*)(ws + 36 * MB);            // 128KB
    float*          cq2  = qn  + NHEADS * NSEQ;
    float*          kn   = cq2 + NHEADS * NSEQ;
    float*          ck   = kn  + NHEADS * NSEQ;
    float*          Opart= (float*)(ws + 37 * MB);            // 16MB
    float*          lpart= (float*)(ws + 53 * MB);            // 256KB
    unsigned short* Ob   = xb;   // xb dead after QKV GEMM

    const dim3 blk(256);

    // 1. fp32 -> bf16 conversions
    convert_inputs<<<3072, blk, 0, stream>>>(x, Wq, Wk, Wv, Wo, xb, Wb, Wob);

    // 2. fused QKV projection + hi/lo split + norms (all in epilogue)
    gemm_bt_bf16<1><<<dim3(NSEQ / 128, 3072 / 128), blk, 0, stream>>>(
        xb, Wb, nullptr, Qh, Ql, qn, cq2, Kh, Kl, kn, ck, Vb);

    // 3. V transpose to [h*64+d][n]
    vt_kernel_bf16<<<dim3(NSEQ / 64, NHEADS), blk, 0, stream>>>(Vb, Vt);

    // 4. attention partials (j-split x2)
    hyp_attn_v2<<<dim3(NSEQ / 64, NHEADS, 2), blk, 0, stream>>>(
        Qh, Ql, Kh, Kl, Vt, qn, cq2, kn, ck, Opart, lpart);

    // 5. merge partials -> Ob (bf16)
    merge_kernel<<<(NSEQ * DMODEL / 8 + 255) / 256, blk, 0, stream>>>(
        Opart, lpart, Ob);

    // 6. output projection
    gemm_bt_bf16<0><<<dim3(NSEQ / 128, DMODEL / 128), blk, 0, stream>>>(
        Ob, Wob, out, nullptr, nullptr, nullptr, nullptr,
        nullptr, nullptr, nullptr, nullptr, nullptr);
}

// Round 7
// 112.345 us; speedup vs baseline: 7.3770x; 1.2351x over previous
//
#include <hip/hip_runtime.h>
#include <math.h>

#define NSEQ   2048
#define DMODEL 1024
#define NHEADS 16
#define HD     64

typedef short bf16x8 __attribute__((ext_vector_type(8)));
typedef float f32x4  __attribute__((ext_vector_type(4)));
typedef unsigned short ushort8_t __attribute__((ext_vector_type(8)));

// RTNE float -> bf16 bits
__device__ __forceinline__ unsigned short f2bf(float x) {
    unsigned int u = __builtin_bit_cast(unsigned int, x);
    unsigned int r = (u + 0x7FFFu + ((u >> 16) & 1u)) >> 16;
    return (unsigned short)r;
}

// ---------------------------------------------------------------------------
// Convert inputs to bf16: x(2M)->xb, Wq/Wk/Wv(3x1M)->Wb[3072][1024], Wo->Wob.
// ---------------------------------------------------------------------------
__global__ __launch_bounds__(256) void convert_inputs(
    const float* __restrict__ x,  const float* __restrict__ Wq,
    const float* __restrict__ Wk, const float* __restrict__ Wv,
    const float* __restrict__ Wo,
    unsigned short* __restrict__ xb, unsigned short* __restrict__ Wb,
    unsigned short* __restrict__ Wob)
{
    const size_t i8 = ((size_t)blockIdx.x * 256 + threadIdx.x) * 8;
    const float* src;
    unsigned short* dst;
    if (i8 < (2ull << 20)) {
        src = x + i8;  dst = xb + i8;
    } else if (i8 < (5ull << 20)) {
        const size_t o = i8 - (2ull << 20);
        const size_t s = o >> 20;
        src = (s == 0 ? Wq : (s == 1 ? Wk : Wv)) + (o & ((1u << 20) - 1));
        dst = Wb + o;
    } else {
        const size_t o = i8 - (5ull << 20);
        src = Wo + o;  dst = Wob + o;
    }
    const float4 v0 = *reinterpret_cast<const float4*>(src);
    const float4 v1 = *reinterpret_cast<const float4*>(src + 4);
    ushort8_t r;
    r[0] = f2bf(v0.x); r[1] = f2bf(v0.y); r[2] = f2bf(v0.z); r[3] = f2bf(v0.w);
    r[4] = f2bf(v1.x); r[5] = f2bf(v1.y); r[6] = f2bf(v1.z); r[7] = f2bf(v1.w);
    *reinterpret_cast<ushort8_t*>(dst) = r;
}

// ---------------------------------------------------------------------------
// bf16 MFMA GEMM (B-transposed): C[m,n] = sum_k A[m,k]*B[n,k], fp32 acc.
// BM=BN=128, BK=64; 4 waves (2x2), wave tile 64x64. Padded-72 LDS rows.
// QKV=1: cols 0-1023 (Q) / 1024-2047 (K): bf16 out + per-(head,row) norms
//        (qn, cq2=2/(1-qn) | kn, ck=1/(1-kn)); cols 2048-3071 (V): bf16 out.
// QKV=0: plain f32 output C0 (N=1024).
// ---------------------------------------------------------------------------
template <int QKV>
__global__ __launch_bounds__(256) void gemm_bt_bf16(
    const unsigned short* __restrict__ A, const unsigned short* __restrict__ B,
    float* __restrict__ C0,
    unsigned short* __restrict__ QbO, float* __restrict__ qnO,
    float* __restrict__ cq2O,
    unsigned short* __restrict__ KbO, float* __restrict__ knO,
    float* __restrict__ ckO,
    unsigned short* __restrict__ VbO)
{
    __shared__ unsigned short Ahs[128 * 72];
    __shared__ unsigned short Bhs[128 * 72];

    const int bm   = blockIdx.x * 128;
    const int bn   = blockIdx.y * 128;
    const int t    = threadIdx.x;
    const int wid  = t >> 6;
    const int lane = t & 63;
    const int g    = lane >> 4;
    const int r    = lane & 15;
    const int wm   = (wid >> 1) * 64;
    const int wn   = (wid & 1) * 64;

    f32x4 acc[4][4];
#pragma unroll
    for (int i = 0; i < 4; ++i)
#pragma unroll
        for (int j = 0; j < 4; ++j) acc[i][j] = (f32x4){0.f, 0.f, 0.f, 0.f};

    const int srow = t >> 1;
    const int sseg = (t & 1) * 32;

    for (int k0 = 0; k0 < DMODEL; k0 += 64) {
        __syncthreads();
        ushort8_t av[4], bv[4];
#pragma unroll
        for (int c = 0; c < 4; ++c) {
            av[c] = *reinterpret_cast<const ushort8_t*>(
                &A[(size_t)(bm + srow) * DMODEL + k0 + sseg + c * 8]);
            bv[c] = *reinterpret_cast<const ushort8_t*>(
                &B[(size_t)(bn + srow) * DMODEL + k0 + sseg + c * 8]);
        }
#pragma unroll
        for (int c = 0; c < 4; ++c) {
            *reinterpret_cast<ushort8_t*>(&Ahs[srow * 72 + sseg + c * 8]) = av[c];
            *reinterpret_cast<ushort8_t*>(&Bhs[srow * 72 + sseg + c * 8]) = bv[c];
        }
        __syncthreads();

#pragma unroll
        for (int dc = 0; dc < 2; ++dc) {
            bf16x8 af[4], bfr[4];
#pragma unroll
            for (int mt = 0; mt < 4; ++mt)
                af[mt] = *reinterpret_cast<const bf16x8*>(
                    &Ahs[(wm + mt * 16 + r) * 72 + dc * 32 + g * 8]);
#pragma unroll
            for (int nt = 0; nt < 4; ++nt)
                bfr[nt] = *reinterpret_cast<const bf16x8*>(
                    &Bhs[(wn + nt * 16 + r) * 72 + dc * 32 + g * 8]);
#pragma unroll
            for (int mt = 0; mt < 4; ++mt)
#pragma unroll
                for (int nt = 0; nt < 4; ++nt)
                    acc[mt][nt] = __builtin_amdgcn_mfma_f32_16x16x32_bf16(
                        af[mt], bfr[nt], acc[mt][nt], 0, 0, 0);
        }
    }

    if (QKV) {
        const int sel = bn >> 10;
        const int bnl = bn & 1023;
        if (sel < 2) {
            unsigned short* Hb = sel ? KbO : QbO;
            float* narr = sel ? knO : qnO;
            float* carr = sel ? ckO : cq2O;
            const int hh = (bnl + wn) >> 6;   // one head per wave (64 cols)
#pragma unroll
            for (int mt = 0; mt < 4; ++mt) {
#pragma unroll
                for (int rg = 0; rg < 4; ++rg) {
                    float ss = 0.f;
#pragma unroll
                    for (int nt = 0; nt < 4; ++nt) {
                        const float v = acc[mt][nt][rg];
                        ss = fmaf(v, v, ss);
                        Hb[(size_t)(bm + wm + mt * 16 + g * 4 + rg) * 1024 +
                           bnl + wn + nt * 16 + r] = f2bf(v);
                    }
                    ss += __shfl_xor(ss, 1, 64);
                    ss += __shfl_xor(ss, 2, 64);
                    ss += __shfl_xor(ss, 4, 64);
                    ss += __shfl_xor(ss, 8, 64);
                    if (r == 0) {
                        const int row = bm + wm + mt * 16 + g * 4 + rg;
                        narr[hh * NSEQ + row] = ss;
                        carr[hh * NSEQ + row] =
                            (sel ? 1.0f : 2.0f) / (1.0f - ss);
                    }
                }
            }
        } else {
#pragma unroll
            for (int mt = 0; mt < 4; ++mt)
#pragma unroll
                for (int nt = 0; nt < 4; ++nt)
#pragma unroll
                    for (int rg = 0; rg < 4; ++rg)
                        VbO[(size_t)(bm + wm + mt * 16 + g * 4 + rg) * 1024 +
                            bnl + wn + nt * 16 + r] = f2bf(acc[mt][nt][rg]);
        }
    } else {
#pragma unroll
        for (int mt = 0; mt < 4; ++mt)
#pragma unroll
            for (int nt = 0; nt < 4; ++nt)
#pragma unroll
                for (int rg = 0; rg < 4; ++rg)
                    C0[(size_t)(bm + wm + mt * 16 + g * 4 + rg) * 1024 +
                       bn + wn + nt * 16 + r] = acc[mt][nt][rg];
    }
}

// ---------------------------------------------------------------------------
// Per-head V transpose (bf16->bf16): Vt[(h*64+d)*2048 + n] = Vb[n*1024+h*64+d]
// ---------------------------------------------------------------------------
__global__ __launch_bounds__(256) void vt_kernel_bf16(
    const unsigned short* __restrict__ Vb, unsigned short* __restrict__ Vt)
{
    __shared__ unsigned short Vs[64 * 72];
    const int h   = blockIdx.y;
    const int n0  = blockIdx.x * 64;
    const int t   = threadIdx.x;
    const int row = t >> 2;
    const int seg = (t & 3) * 16;

    const unsigned short* src = Vb + (size_t)(n0 + row) * 1024 + h * HD + seg;
    *reinterpret_cast<ushort8_t*>(&Vs[row * 72 + seg]) =
        *reinterpret_cast<const ushort8_t*>(src);
    *reinterpret_cast<ushort8_t*>(&Vs[row * 72 + seg + 8]) =
        *reinterpret_cast<const ushort8_t*>(src + 8);
    __syncthreads();

    ushort8_t a, b;
#pragma unroll
    for (int c = 0; c < 8; ++c) a[c] = Vs[(seg + c) * 72 + row];
#pragma unroll
    for (int c = 0; c < 8; ++c) b[c] = Vs[(seg + 8 + c) * 72 + row];
    unsigned short* dst = Vt + (size_t)(h * HD + row) * NSEQ + n0 + seg;
    *reinterpret_cast<ushort8_t*>(dst)     = a;
    *reinterpret_cast<ushort8_t*>(dst + 8) = b;
}

// ---------------------------------------------------------------------------
// MFMA hyperbolic attention v3.
// Grid (NSEQ/64, NHEADS, 2). 256 thr = 4 waves; wave w: q rows [n0+16w,+16).
// Single-pass bf16 QK (error analysis: dsq ~ 42+-26, never near 0; qk err
// ~7e-3 -> output err ~3e-6). Linear 128B LDS rows + XOR colseg swizzle
// (c ^= row&7) on K/V/P: all b128 fragment reads and staging writes derived
// conflict-free (<=2-way). kn/ck via direct L2 scalar loads.
// Weights: w = ca - sqrt(ca^2-1) = exp(-acosh(ca)); only fmax(ca,1) kept
// (subsumes boundary w=1 and sqrt-negative safety).
// ---------------------------------------------------------------------------
__global__ __launch_bounds__(256) void hyp_attn_v3(
    const unsigned short* __restrict__ Qb, const unsigned short* __restrict__ Kb,
    const unsigned short* __restrict__ Vt,
    const float* __restrict__ qn_a, const float* __restrict__ cq2_a,
    const float* __restrict__ kn_a, const float* __restrict__ ck_a,
    float* __restrict__ Opart, float* __restrict__ lpart)
{
    __shared__ unsigned short Khs[64 * 64];   // [j][k-seg swz]
    __shared__ unsigned short Vts[64 * 64];   // [d][j-seg swz]
    __shared__ unsigned short Ps[4][16 * 64]; // per-wave [q][j-seg swz]

    const int h    = blockIdx.y;
    const int n0   = blockIdx.x * 64;
    const int jh   = blockIdx.z;
    const int t    = threadIdx.x;
    const int wid  = t >> 6;
    const int lane = t & 63;
    const int g    = lane >> 4;
    const int r    = lane & 15;
    const int qb   = n0 + wid * 16;

    // Q A-frags: Q[qb+r][k = dc*32 + g*8 + e]
    bf16x8 qf[2];
#pragma unroll
    for (int dc = 0; dc < 2; ++dc)
        qf[dc] = *reinterpret_cast<const bf16x8*>(
            Qb + (size_t)(qb + r) * DMODEL + h * HD + dc * 32 + g * 8);

    // per-q constants for the 4 D-rows this thread owns (q = qb + g*4 + rg)
    float qn_r[4], c2q[4];
#pragma unroll
    for (int rg = 0; rg < 4; ++rg) {
        qn_r[rg] = qn_a[h * NSEQ + qb + g * 4 + rg];
        c2q[rg]  = cq2_a[h * NSEQ + qb + g * 4 + rg];
    }

    f32x4 oacc[4];
#pragma unroll
    for (int nt = 0; nt < 4; ++nt) oacc[nt] = (f32x4){0.f, 0.f, 0.f, 0.f};
    float l_acc[4] = {0.f, 0.f, 0.f, 0.f};

    const int srow = t >> 2;           // 0..63 (LDS row this thread fills)
    const int c0   = (t & 3) * 2;      // first of two 8-u16 col segments
    const int sw0  = (c0 ^ (srow & 7)) * 8;
    const int sw1  = ((c0 + 1) ^ (srow & 7)) * 8;
    const int sg   = (t & 3) * 16;     // global col offset (u16)
    unsigned short* Pw = &Ps[wid][0];

    for (int tb = 0; tb < 16; ++tb) {
        const int j0 = jh * 1024 + tb * 64;
        __syncthreads();
        // ---- stage K and V^T tiles (vector loads, swizzled LDS writes) ----
        {
            const unsigned short* ks = Kb + (size_t)(j0 + srow) * DMODEL + h * HD + sg;
            const unsigned short* vs = Vt + (size_t)(h * HD + srow) * NSEQ + j0 + sg;
            *reinterpret_cast<ushort8_t*>(&Khs[srow * 64 + sw0]) =
                *reinterpret_cast<const ushort8_t*>(ks);
            *reinterpret_cast<ushort8_t*>(&Khs[srow * 64 + sw1]) =
                *reinterpret_cast<const ushort8_t*>(ks + 8);
            *reinterpret_cast<ushort8_t*>(&Vts[srow * 64 + sw0]) =
                *reinterpret_cast<const ushort8_t*>(vs);
            *reinterpret_cast<ushort8_t*>(&Vts[srow * 64 + sw1]) =
                *reinterpret_cast<const ushort8_t*>(vs + 8);
        }
        __syncthreads();

        // ---- S tiles + distance -> w -> P (swizzled wave-private LDS) ----
#pragma unroll
        for (int jt = 0; jt < 4; ++jt) {
            f32x4 sac = (f32x4){0.f, 0.f, 0.f, 0.f};
#pragma unroll
            for (int dc = 0; dc < 2; ++dc) {
                const bf16x8 kb = *reinterpret_cast<const bf16x8*>(
                    &Khs[(jt * 16 + r) * 64 + ((dc * 4 + g) ^ (r & 7)) * 8]);
                sac = __builtin_amdgcn_mfma_f32_16x16x32_bf16(qf[dc], kb, sac, 0, 0, 0);
            }
            const int jj = j0 + jt * 16 + r;
            const float kn_v = kn_a[h * NSEQ + jj];
            const float ck_v = ck_a[h * NSEQ + jj];
#pragma unroll
            for (int rg = 0; rg < 4; ++rg) {
                const float dsq = fmaf(-2.f, sac[rg], qn_r[rg] + kn_v);
                const float ca  = fmaxf(fmaf(dsq, c2q[rg] * ck_v, 1.f), 1.0f);
                const float s2  = fmaf(ca, ca, -1.f);
                const float wj  = ca - __builtin_amdgcn_sqrtf(s2);
                l_acc[rg] += wj;
                const int qrow = g * 4 + rg;
                Pw[qrow * 64 +
                   ((2 * jt + (r >> 3)) ^ (qrow & 7)) * 8 + (r & 7)] = f2bf(wj);
            }
        }
        // Pw is wave-private: within-wave ds ordering suffices

        // ---- PV: O[q][d] += P . V ----
#pragma unroll
        for (int kc = 0; kc < 2; ++kc) {
            const bf16x8 pa = *reinterpret_cast<const bf16x8*>(
                &Pw[r * 64 + ((kc * 4 + g) ^ (r & 7)) * 8]);   // A: m=r(q), k=j
#pragma unroll
            for (int nt = 0; nt < 4; ++nt) {
                const bf16x8 vb = *reinterpret_cast<const bf16x8*>(
                    &Vts[(nt * 16 + r) * 64 + ((kc * 4 + g) ^ (r & 7)) * 8]);
                oacc[nt] = __builtin_amdgcn_mfma_f32_16x16x32_bf16(pa, vb, oacc[nt], 0, 0, 0);
            }
        }
    }

    // ---- l reduce over the 16 r-lanes ----
#pragma unroll
    for (int rg = 0; rg < 4; ++rg) {
        l_acc[rg] += __shfl_xor(l_acc[rg], 1, 64);
        l_acc[rg] += __shfl_xor(l_acc[rg], 2, 64);
        l_acc[rg] += __shfl_xor(l_acc[rg], 4, 64);
        l_acc[rg] += __shfl_xor(l_acc[rg], 8, 64);
    }

    // ---- write partials ----
    float* Op = Opart + (size_t)jh * NSEQ * DMODEL;
#pragma unroll
    for (int nt = 0; nt < 4; ++nt)
#pragma unroll
        for (int rg = 0; rg < 4; ++rg)
            Op[(size_t)(qb + g * 4 + rg) * DMODEL + h * HD + nt * 16 + r] =
                oacc[nt][rg];
    if (r == 0) {
#pragma unroll
        for (int rg = 0; rg < 4; ++rg)
            lpart[(jh * NHEADS + h) * NSEQ + qb + g * 4 + rg] = l_acc[rg];
    }
}

// ---------------------------------------------------------------------------
// Merge j-split partials: Ob = bf16((O0+O1) / (l0+l1)).
// ---------------------------------------------------------------------------
__global__ __launch_bounds__(256) void merge_kernel(
    const float* __restrict__ Opart, const float* __restrict__ lpart,
    unsigned short* __restrict__ Ob)
{
    const size_t i8 = ((size_t)blockIdx.x * 256 + threadIdx.x) * 8;
    if (i8 >= (size_t)NSEQ * DMODEL) return;
    const int n  = (int)(i8 >> 10);
    const int dm = (int)(i8 & 1023);
    const int h  = dm >> 6;
    const float li = 1.0f / (lpart[h * NSEQ + n] +
                             lpart[(NHEADS + h) * NSEQ + n]);
    const float* O0 = Opart + i8;
    const float* O1 = Opart + (size_t)NSEQ * DMODEL + i8;
    ushort8_t o;
#pragma unroll
    for (int c = 0; c < 2; ++c) {
        const float4 a = *reinterpret_cast<const float4*>(O0 + c * 4);
        const float4 b = *reinterpret_cast<const float4*>(O1 + c * 4);
        o[c * 4 + 0] = f2bf((a.x + b.x) * li);
        o[c * 4 + 1] = f2bf((a.y + b.y) * li);
        o[c * 4 + 2] = f2bf((a.z + b.z) * li);
        o[c * 4 + 3] = f2bf((a.w + b.w) * li);
    }
    *reinterpret_cast<ushort8_t*>(Ob + i8) = o;
}

// ---------------------------------------------------------------------------
extern "C" void kernel_launch(void* const* d_in, const int* in_sizes, int n_in,
                              void* d_out, int out_size, void* d_ws, size_t ws_size,
                              hipStream_t stream)
{
    const float* x  = (const float*)d_in[0];
    const float* Wq = (const float*)d_in[1];
    const float* Wk = (const float*)d_in[2];
    const float* Wv = (const float*)d_in[3];
    const float* Wo = (const float*)d_in[4];
    float* out = (float*)d_out;

    char* ws = (char*)d_ws;
    const size_t MB = 1048576;
    unsigned short* xb   = (unsigned short*)(ws);             // 4MB (-> Ob)
    unsigned short* Wb   = (unsigned short*)(ws + 4  * MB);   // 6MB
    unsigned short* Wob  = (unsigned short*)(ws + 10 * MB);   // 2MB
    unsigned short* Qbuf = (unsigned short*)(ws + 12 * MB);   // 4MB
    unsigned short* Kbuf = (unsigned short*)(ws + 16 * MB);   // 4MB
    unsigned short* Vb   = (unsigned short*)(ws + 20 * MB);   // 4MB
    unsigned short* Vt   = (unsigned short*)(ws + 24 * MB);   // 4MB
    float*          qn   = (float*)(ws + 28 * MB);            // 128KB
    float*          cq2  = qn  + NHEADS * NSEQ;
    float*          kn   = cq2 + NHEADS * NSEQ;
    float*          ck   = kn  + NHEADS * NSEQ;
    float*          Opart= (float*)(ws + 29 * MB);            // 16MB
    float*          lpart= (float*)(ws + 45 * MB);            // 256KB
    unsigned short* Ob   = xb;   // xb dead after QKV GEMM

    const dim3 blk(256);

    // 1. fp32 -> bf16 conversions
    convert_inputs<<<3072, blk, 0, stream>>>(x, Wq, Wk, Wv, Wo, xb, Wb, Wob);

    // 2. fused QKV projection (bf16 out) + norms in epilogue
    gemm_bt_bf16<1><<<dim3(NSEQ / 128, 3072 / 128), blk, 0, stream>>>(
        xb, Wb, nullptr, Qbuf, qn, cq2, Kbuf, kn, ck, Vb);

    // 3. V transpose to [h*64+d][n]
    vt_kernel_bf16<<<dim3(NSEQ / 64, NHEADS), blk, 0, stream>>>(Vb, Vt);

    // 4. attention partials (j-split x2)
    hyp_attn_v3<<<dim3(NSEQ / 64, NHEADS, 2), blk, 0, stream>>>(
        Qbuf, Kbuf, Vt, qn, cq2, kn, ck, Opart, lpart);

    // 5. merge partials -> Ob (bf16)
    merge_kernel<<<(NSEQ * DMODEL / 8 + 255) / 256, blk, 0, stream>>>(
        Opart, lpart, Ob);

    // 6. output projection
    gemm_bt_bf16<0><<<dim3(NSEQ / 128, DMODEL / 128), blk, 0, stream>>>(
        Ob, Wob, out, nullptr, nullptr, nullptr,
        nullptr, nullptr, nullptr, nullptr);
}